// Round 3
// baseline (319.428 us; speedup 1.0000x reference)
//
#include <hip/hip_runtime.h>
#include <cstdint>

#define DIMC 2048
#define NSEQ 2048
#define BATCH 2
#define NH 16
#define HD 128
#define MROWS 4096            // BATCH*NSEQ
#define NQKV 6144             // 3*DIMC
#define QSCALE 0.08838834764831845f

typedef float f32x4 __attribute__((ext_vector_type(4)));
typedef __bf16 bf16x8 __attribute__((ext_vector_type(8)));
typedef __bf16 bf16x4 __attribute__((ext_vector_type(4)));

__device__ __forceinline__ f32x4 mfma16(bf16x8 a, bf16x8 b, f32x4 c) {
  return __builtin_amdgcn_mfma_f32_16x16x32_bf16(a, b, c, 0, 0, 0);
}

typedef __attribute__((address_space(1))) void gvoid;
typedef __attribute__((address_space(3))) void ldsvoid;

__device__ __forceinline__ void async16(void* lds, const void* g) {
  __builtin_amdgcn_global_load_lds((gvoid*)(uintptr_t)g, (ldsvoid*)(uintptr_t)lds, 16, 0, 0);
}

// raw barrier: no vmcnt drain (unlike __syncthreads); "memory" clobber pins
// LDS loads / stage intrinsics on their side of the barrier.
#define BAR() asm volatile("s_barrier" ::: "memory")
#define VMCNT(n) asm volatile("s_waitcnt vmcnt(" #n ")" ::: "memory")

// ---------------------------------------------------------------------------
// fp32 -> bf16 cast
// ---------------------------------------------------------------------------
__global__ __launch_bounds__(256) void cast_bf16(const float* __restrict__ src,
                                                 __bf16* __restrict__ dst, int n) {
  int i = (blockIdx.x * 256 + threadIdx.x) * 4;
  const int stride = gridDim.x * 1024;
  for (; i < n; i += stride) {
    const float4 v = *(const float4*)(src + i);
    bf16x4 o = {(__bf16)v.x, (__bf16)v.y, (__bf16)v.z, (__bf16)v.w};
    *(bf16x4*)(dst + i) = o;
  }
}

// ---------------------------------------------------------------------------
// QKV GEMM, 256x256 tile, BK=64, 8 waves (2Mx4N), 8-phase pipelined schedule.
// C[M][N] = A[M][K] * B[N][K]^T; K=2048 (NT=32 K-tiles, 16 iterations).
// LDS 128KiB: 2 buffers x { A[2 halves][128][64], B[2 halves][128][64] } bf16.
// st_16x32 swizzle (byte ^= ((off>>9)&1)<<5 within each half) applied via
// pre-swizzled GLOBAL source (linear global_load_lds dest) + swizzled ds_read.
// Schedule (per iter i: p0-3 compute buf0=tile 2i, p4-7 buf1=tile 2i+1):
//   p0: issue buf1.A1,A3(t=2i+1); vmcnt(8); BAR; read Ball+Aq0; MFMA16; BAR
//   p1: read Aq1; issue buf0.B0,B1(t=2i+2);             BAR; MFMA16; BAR
//   p2: read Aq2; issue buf0.B2,B3,A0,A2(t=2i+2);       BAR; MFMA16; BAR
//   p3: read Aq3;                                       BAR; MFMA16; BAR
//   p4: issue buf0.A1,A3(t=2i+2); vmcnt(8); BAR; read Ball+Aq0; MFMA16; BAR
//   p5: read Aq1; issue buf1.B0,B1(t=2i+3);             BAR; MFMA16; BAR
//   p6: read Aq2; issue buf1.B2,B3,A0,A2(t=2i+3);       BAR; MFMA16; BAR
//   p7: read Aq3;                                       BAR; MFMA16; BAR
// Every stage-issue strictly follows (with >=1 barrier) the last read of the
// region it overwrites; vmcnt(8) exactly retires the tile about to be read.
// ---------------------------------------------------------------------------
#define RA 0
#define RB 32768
#define BUF1 65536

#define READ_B(Bb) do { \
    bfr[0][0]=ldf(Bb,rB,0);      bfr[0][1]=ldf(Bb,rB,1); \
    bfr[1][0]=ldf(Bb,rB+16,0);   bfr[1][1]=ldf(Bb,rB+16,1); \
    bfr[2][0]=ldf(Bb,rB+32,0);   bfr[2][1]=ldf(Bb,rB+32,1); \
    bfr[3][0]=ldf(Bb,rB+48,0);   bfr[3][1]=ldf(Bb,rB+48,1); } while(0)

#define READ_A(Ab,P) do { \
    afr[0][0]=ldf(Ab,(P*2+0)*16+a,0); afr[0][1]=ldf(Ab,(P*2+0)*16+a,1); \
    afr[1][0]=ldf(Ab,(P*2+1)*16+a,0); afr[1][1]=ldf(Ab,(P*2+1)*16+a,1); } while(0)

#define DO_MFMA(P) do { __builtin_amdgcn_s_setprio(1); \
    _Pragma("unroll") for (int f_=0; f_<2; ++f_) \
    _Pragma("unroll") for (int n_=0; n_<4; ++n_) \
    _Pragma("unroll") for (int k_=0; k_<2; ++k_) \
      acc[P*2+f_][n_] = mfma16(afr[f_][k_], bfr[n_][k_], acc[P*2+f_][n_]); \
    __builtin_amdgcn_s_setprio(0); } while(0)

__global__ __launch_bounds__(512, 2) void qkv256(
    const __bf16* __restrict__ A, const __bf16* __restrict__ Bm,
    __bf16* __restrict__ Qb, __bf16* __restrict__ Kb, __bf16* __restrict__ Vtb,
    const float* __restrict__ bq, const float* __restrict__ bk,
    const float* __restrict__ bv) {
  extern __shared__ __align__(16) char Lds[];
  const int tid = threadIdx.x;
  const int l = tid & 63, w = tid >> 6;
  const int a = l & 15, g = l >> 4;
  const int wm = w >> 2, wn = w & 3;
  const int mbase = blockIdx.y * 256, nbase = blockIdx.x * 256;
  const int wbyte = w * 1024;
  const char* Ag = (const char*)A;
  const char* Bg = (const char*)Bm;
  const int rB = (wn & 1) * 64 + a;

  f32x4 acc[8][4] = {};
  bf16x8 bfr[4][2], afr[2][2];

  // stage one 8KB op: op j = half (j>>1), rows (j&1)*64..+63 of a [2][128][64]
  // bf16 region. LDS dest linear; global source column pre-swizzled (rule 21).
  auto issue = [&](int bufofs, int regofs, const char* gmat, int grow0, int kt, int j) {
    const int grow = grow0 + (j >> 1) * 128 + (j & 1) * 64 + (tid >> 3);
    const int scol = ((tid & 7) * 16) ^ (((tid >> 5) & 1) << 5);
    async16(Lds + bufofs + regofs + j * 8192 + wbyte,
            gmat + (size_t)grow * (DIMC * 2) + kt * 128 + scol);
  };
  // swizzled fragment read: 16B at (row, k-slice ks), bank-spread by row bit 2.
  auto ldf = [&](const char* halfbase, int row, int ks) -> bf16x8 {
    const int c = (ks * 64 + g * 16) ^ (((row >> 2) & 1) << 5);
    return *(const bf16x8*)(halfbase + row * 128 + c);
  };

  // prologue: buf0 <- tile0 (all 8 ops), buf1 <- tile1 (first 6 ops)
  issue(0, RB, Bg, nbase, 0, 0); issue(0, RB, Bg, nbase, 0, 1);
  issue(0, RB, Bg, nbase, 0, 2); issue(0, RB, Bg, nbase, 0, 3);
  issue(0, RA, Ag, mbase, 0, 0); issue(0, RA, Ag, mbase, 0, 2);
  issue(0, RA, Ag, mbase, 0, 1); issue(0, RA, Ag, mbase, 0, 3);
  issue(BUF1, RB, Bg, nbase, 1, 0); issue(BUF1, RB, Bg, nbase, 1, 1);
  issue(BUF1, RB, Bg, nbase, 1, 2); issue(BUF1, RB, Bg, nbase, 1, 3);
  issue(BUF1, RA, Ag, mbase, 1, 0); issue(BUF1, RA, Ag, mbase, 1, 2);

  const char* A0 = Lds + wm * 16384;
  const char* B0 = Lds + RB + (wn >> 1) * 16384;
  const char* A1 = A0 + BUF1;
  const char* B1 = B0 + BUF1;

  for (int i = 0; i < 16; ++i) {
    const bool more = (i < 15);
    const int t2 = 2 * i + 2, t3 = 2 * i + 3;
    // ---- p0 ----
    issue(BUF1, RA, Ag, mbase, 2 * i + 1, 1);
    issue(BUF1, RA, Ag, mbase, 2 * i + 1, 3);
    VMCNT(8); BAR();
    READ_B(B0); READ_A(A0, 0);
    DO_MFMA(0); BAR();
    // ---- p1 ----
    READ_A(A0, 1);
    if (more) { issue(0, RB, Bg, nbase, t2, 0); issue(0, RB, Bg, nbase, t2, 1); }
    BAR(); DO_MFMA(1); BAR();
    // ---- p2 ----
    READ_A(A0, 2);
    if (more) { issue(0, RB, Bg, nbase, t2, 2); issue(0, RB, Bg, nbase, t2, 3);
                issue(0, RA, Ag, mbase, t2, 0); issue(0, RA, Ag, mbase, t2, 2); }
    BAR(); DO_MFMA(2); BAR();
    // ---- p3 ----
    READ_A(A0, 3);
    BAR(); DO_MFMA(3); BAR();
    // ---- p4 ----
    if (more) { issue(0, RA, Ag, mbase, t2, 1); issue(0, RA, Ag, mbase, t2, 3);
                VMCNT(8); } else { VMCNT(0); }
    BAR();
    READ_B(B1); READ_A(A1, 0);
    DO_MFMA(0); BAR();
    // ---- p5 ----
    READ_A(A1, 1);
    if (more) { issue(BUF1, RB, Bg, nbase, t3, 0); issue(BUF1, RB, Bg, nbase, t3, 1); }
    BAR(); DO_MFMA(1); BAR();
    // ---- p6 ----
    READ_A(A1, 2);
    if (more) { issue(BUF1, RB, Bg, nbase, t3, 2); issue(BUF1, RB, Bg, nbase, t3, 3);
                issue(BUF1, RA, Ag, mbase, t3, 0); issue(BUF1, RA, Ag, mbase, t3, 2); }
    BAR(); DO_MFMA(2); BAR();
    // ---- p7 ----
    READ_A(A1, 3);
    BAR(); DO_MFMA(3); BAR();
  }

  // epilogue: bias + scatter Q[B,H,N,D]*scale, K[B,H,N,D], Vt[B,H,D,N]
  const int seg = nbase >> 11;
  const int cin = (nbase & 2047) + wn * 64;
  const float* bias = (seg == 0) ? bq : ((seg == 1) ? bk : bv);
  const float scl = (seg == 0) ? QSCALE : 1.0f;
#pragma unroll
  for (int n = 0; n < 4; ++n) {
    const int c = cin + n * 16 + a;
    const float bb = bias[c];
    const int h = c >> 7, d = c & 127;
#pragma unroll
    for (int m = 0; m < 8; ++m) {
      const int mr = mbase + wm * 128 + m * 16 + g * 4;
      const int b_ = mr >> 11, sq = mr & 2047;
      f32x4 v = acc[m][n];
      if (seg == 2) {
        __bf16* dst = Vtb + ((size_t)(b_ * NH + h) * HD + d) * NSEQ + sq;
        bf16x4 pk = {(__bf16)(v[0] + bb), (__bf16)(v[1] + bb),
                     (__bf16)(v[2] + bb), (__bf16)(v[3] + bb)};
        *(bf16x4*)dst = pk;
      } else {
        __bf16* dst = ((seg == 0) ? Qb : Kb) +
                      ((size_t)(b_ * NH + h) * NSEQ + sq) * HD + d;
#pragma unroll
        for (int j = 0; j < 4; ++j) dst[(size_t)j * HD] = (__bf16)((v[j] + bb) * scl);
      }
    }
  }
}

// ---------------------------------------------------------------------------
// m97-structure 128x128 GEMM kept for the output projection (its 128-block
// grid would leave half the chip idle at 256x256).
// ---------------------------------------------------------------------------
__global__ __launch_bounds__(256) void gemm_out(
    const __bf16* __restrict__ A, const __bf16* __restrict__ Bm,
    const float* __restrict__ bias0, float* __restrict__ outp) {
  __shared__ __bf16 Al[128 * 32];
  __shared__ __bf16 Bl[128 * 32];
  const int tid = threadIdx.x;
  const int w = tid >> 6, l = tid & 63;
  const int a = l & 15, g = l >> 4;
  const int mbase = blockIdx.y * 128, nbase = blockIdx.x * 128;
  const int wr = w >> 1, wc = w & 1;

  f32x4 acc[4][4] = {};

  const char* Ag = (const char*)A +
      ((size_t)(mbase + w * 32 + (l >> 2)) * DIMC + (size_t)(l & 3) * 8) * 2;
  const char* Bg = (const char*)Bm +
      ((size_t)(nbase + w * 32 + (l >> 2)) * DIMC + (size_t)(l & 3) * 8) * 2;
  char* Alw = (char*)Al + w * 2048;
  char* Blw = (char*)Bl + w * 2048;

  for (int kt = 0; kt < DIMC / 32; ++kt) {
    const size_t ko = (size_t)kt * 64;
    async16(Alw, Ag + ko);
    async16(Alw + 1024, Ag + (size_t)16 * (DIMC * 2) + ko);
    async16(Blw, Bg + ko);
    async16(Blw + 1024, Bg + (size_t)16 * (DIMC * 2) + ko);
    __syncthreads();
    bf16x8 af[4], bf_[4];
#pragma unroll
    for (int m = 0; m < 4; ++m)
      af[m] = *(const bf16x8*)((const char*)Al + (wr * 64 + m * 16 + a) * 64 + g * 16);
#pragma unroll
    for (int n = 0; n < 4; ++n)
      bf_[n] = *(const bf16x8*)((const char*)Bl + (wc * 64 + n * 16 + a) * 64 + g * 16);
#pragma unroll
    for (int m = 0; m < 4; ++m)
#pragma unroll
      for (int n = 0; n < 4; ++n) acc[m][n] = mfma16(af[m], bf_[n], acc[m][n]);
    __syncthreads();
  }

#pragma unroll
  for (int n = 0; n < 4; ++n) {
    const int c = nbase + wc * 64 + n * 16 + a;
    const float bb = bias0[c];
#pragma unroll
    for (int m = 0; m < 4; ++m) {
      const int mr = mbase + wr * 64 + m * 16 + g * 4;
      float* dst = outp + (size_t)mr * DIMC + c;
      f32x4 v = acc[m][n];
#pragma unroll
      for (int j = 0; j < 4; ++j) dst[(size_t)j * DIMC] = v[j] + bb;
    }
  }
}

// ---------------------------------------------------------------------------
// Sliding-window flash attention (unchanged from validated baseline).
// ---------------------------------------------------------------------------
__global__ __launch_bounds__(256) void attn_swa(const __bf16* __restrict__ Qb,
                                                const __bf16* __restrict__ Kb,
                                                const __bf16* __restrict__ Vtb,
                                                __bf16* __restrict__ Ob) {
  __shared__ __bf16 Klds[64 * 128];
  __shared__ __bf16 Vlds[128 * 64];
  __shared__ __bf16 Plds[4 * 16 * 64];
  const int tid = threadIdx.x;
  const int w = tid >> 6, l = tid & 63;
  const int a = l & 15, g = l >> 4;
  const int bh = blockIdx.y;
  const int qbase = blockIdx.x * 64;
  const __bf16* Qg = Qb + (size_t)bh * NSEQ * HD + (size_t)qbase * HD;
  const __bf16* Kg = Kb + (size_t)bh * NSEQ * HD;
  const __bf16* Vg = Vtb + (size_t)bh * HD * NSEQ;

  bf16x8 qf[4];
#pragma unroll
  for (int s = 0; s < 4; ++s)
    qf[s] = *(const bf16x8*)(Qg + (size_t)(w * 16 + a) * HD + s * 32 + g * 8);

  float mrow[4] = {-1e38f, -1e38f, -1e38f, -1e38f};
  float lrow[4] = {0.f, 0.f, 0.f, 0.f};
  f32x4 o[8] = {};

  const int ktlo = (qbase >= 1024) ? ((qbase - 1024) >> 6) : 0;
  const int kthi = qbase >> 6;
  const int qmax = qbase + 63;

  for (int kt = ktlo; kt <= kthi; ++kt) {
    const int kb = kt * 64;
#pragma unroll
    for (int j = 0; j < 4; ++j) {
      const int off = j * 4096 + w * 1024 + l * 16;
      const int row = off >> 8;
      const int cg = ((off >> 4) & 15) ^ (row & 7);
      async16((char*)Klds + j * 4096 + w * 1024,
              (const char*)Kg + (size_t)(kb + row) * 256 + cg * 16);
    }
#pragma unroll
    for (int j = 0; j < 4; ++j) {
      const int off = j * 4096 + w * 1024 + l * 16;
      const int row = off >> 7;
      const int cg = ((off >> 4) & 7) ^ (row & 7);
      async16((char*)Vlds + j * 4096 + w * 1024,
              (const char*)Vg + (size_t)row * (NSEQ * 2) + (size_t)kb * 2 + cg * 16);
    }
    __syncthreads();

    const bool full = (kb >= qmax - 1024) && (kb + 63 <= qbase);
    f32x4 s4[4];
#pragma unroll
    for (int t = 0; t < 4; ++t) {
      f32x4 sc = {};
#pragma unroll
      for (int ds = 0; ds < 4; ++ds) {
        const int row = t * 16 + a;
        const int ch = (ds * 4 + g) ^ (row & 7);
        bf16x8 kf = *(const bf16x8*)((const char*)Klds + row * 256 + ch * 16);
        sc = mfma16(qf[ds], kf, sc);
      }
      s4[t] = sc;
    }
    if (!full) {
#pragma unroll
      for (int t = 0; t < 4; ++t)
#pragma unroll
        for (int i = 0; i < 4; ++i) {
          const int q = qbase + w * 16 + g * 4 + i;
          const int kv = kb + t * 16 + a;
          if (kv > q || kv + 1024 < q) s4[t][i] = -1e30f;
        }
    }
    float pm[4], corr[4], rs[4];
#pragma unroll
    for (int i = 0; i < 4; ++i)
      pm[i] = fmaxf(fmaxf(s4[0][i], s4[1][i]), fmaxf(s4[2][i], s4[3][i]));
#pragma unroll
    for (int i = 0; i < 4; ++i) {
      pm[i] = fmaxf(pm[i], __shfl_xor(pm[i], 1));
      pm[i] = fmaxf(pm[i], __shfl_xor(pm[i], 2));
      pm[i] = fmaxf(pm[i], __shfl_xor(pm[i], 4));
      pm[i] = fmaxf(pm[i], __shfl_xor(pm[i], 8));
      const float nm = fmaxf(mrow[i], pm[i]);
      corr[i] = __expf(mrow[i] - nm);
      mrow[i] = nm;
      rs[i] = 0.f;
    }
#pragma unroll
    for (int t = 0; t < 4; ++t)
#pragma unroll
      for (int i = 0; i < 4; ++i) {
        const float p = __expf(s4[t][i] - mrow[i]);
        s4[t][i] = p;
        rs[i] += p;
      }
#pragma unroll
    for (int i = 0; i < 4; ++i) {
      rs[i] += __shfl_xor(rs[i], 1);
      rs[i] += __shfl_xor(rs[i], 2);
      rs[i] += __shfl_xor(rs[i], 4);
      rs[i] += __shfl_xor(rs[i], 8);
      lrow[i] = lrow[i] * corr[i] + rs[i];
    }
#pragma unroll
    for (int n = 0; n < 8; ++n)
#pragma unroll
      for (int i = 0; i < 4; ++i) o[n][i] *= corr[i];
    char* Pw = (char*)Plds + w * 2048;
#pragma unroll
    for (int t = 0; t < 4; ++t)
#pragma unroll
      for (int i = 0; i < 4; ++i) {
        const int q = g * 4 + i;
        const int byte = (q * 128 + (t * 16 + a) * 2) ^ ((q & 7) << 4);
        *(__bf16*)(Pw + byte) = (__bf16)s4[t][i];
      }
#pragma unroll
    for (int ks = 0; ks < 2; ++ks) {
      const int ch = (ks * 4 + g) ^ (a & 7);
      bf16x8 pa = *(const bf16x8*)(Pw + a * 128 + ch * 16);
#pragma unroll
      for (int n = 0; n < 8; ++n) {
        const int row = n * 16 + a;
        const int vch = (ks * 4 + g) ^ (row & 7);
        bf16x8 vf = *(const bf16x8*)((const char*)Vlds + row * 128 + vch * 16);
        o[n] = mfma16(pa, vf, o[n]);
      }
    }
    __syncthreads();
  }

  const int b_ = bh >> 4, h = bh & 15;
  __bf16* Og = Ob + (size_t)(b_ * NSEQ + qbase + w * 16 + g * 4) * DIMC + h * HD;
#pragma unroll
  for (int i = 0; i < 4; ++i) {
    const float inv = 1.f / lrow[i];
#pragma unroll
    for (int n = 0; n < 8; ++n)
      Og[(size_t)i * DIMC + n * 16 + a] = (__bf16)(o[n][i] * inv);
  }
}

// ---------------------------------------------------------------------------
extern "C" void kernel_launch(void* const* d_in, const int* in_sizes, int n_in,
                              void* d_out, int out_size, void* d_ws, size_t ws_size,
                              hipStream_t stream) {
  const float* x = (const float*)d_in[0];
  const float* Wq = (const float*)d_in[1];
  const float* bq = (const float*)d_in[2];
  const float* Wk = (const float*)d_in[3];
  const float* bk = (const float*)d_in[4];
  const float* Wv = (const float*)d_in[5];
  const float* bv = (const float*)d_in[6];
  const float* Wo = (const float*)d_in[7];
  const float* bo = (const float*)d_in[8];
  float* out = (float*)d_out;

  char* ws = (char*)d_ws;
  __bf16* xb    = (__bf16*)(ws + 0);          // 16.78 MB (reused as Ob)
  __bf16* Wqkvb = (__bf16*)(ws + 16777216);   // 25.17 MB
  __bf16* Wob   = (__bf16*)(ws + 41943040);   // 8.39 MB
  __bf16* Qb    = (__bf16*)(ws + 50331648);   // 16.78 MB
  __bf16* Kb    = (__bf16*)(ws + 67108864);   // 16.78 MB
  __bf16* Vtb   = (__bf16*)(ws + 83886080);   // 16.78 MB -> total 100.66 MB
  __bf16* Ob    = xb;

  // allow 128 KiB dynamic LDS for qkv256 (idempotent; first call is outside
  // graph capture so the attribute persists)
  (void)hipFuncSetAttribute((const void*)qkv256,
                            hipFuncAttributeMaxDynamicSharedMemorySize, 131072);

  cast_bf16<<<dim3(2048), 256, 0, stream>>>(x, xb, MROWS * DIMC);
  cast_bf16<<<dim3(1024), 256, 0, stream>>>(Wq, Wqkvb, DIMC * DIMC);
  cast_bf16<<<dim3(1024), 256, 0, stream>>>(Wk, Wqkvb + (size_t)DIMC * DIMC, DIMC * DIMC);
  cast_bf16<<<dim3(1024), 256, 0, stream>>>(Wv, Wqkvb + (size_t)2 * DIMC * DIMC, DIMC * DIMC);
  cast_bf16<<<dim3(1024), 256, 0, stream>>>(Wo, Wob, DIMC * DIMC);

  qkv256<<<dim3(NQKV / 256, MROWS / 256), 512, 131072, stream>>>(
      xb, Wqkvb, Qb, Kb, Vtb, bq, bk, bv);

  attn_swa<<<dim3(NSEQ / 64, BATCH * NH), 256, 0, stream>>>(Qb, Kb, Vtb, Ob);

  gemm_out<<<dim3(DIMC / 128, MROWS / 128), 256, 0, stream>>>(
      Ob, Wob, bo, out);
}

// Round 4
// 308.112 us; speedup vs baseline: 1.0367x; 1.0367x over previous
//
#include <hip/hip_runtime.h>
#include <cstdint>

#define DIMC 2048
#define NSEQ 2048
#define BATCH 2
#define NH 16
#define HD 128
#define MROWS 4096            // BATCH*NSEQ
#define NQKV 6144             // 3*DIMC
#define QSCALE 0.08838834764831845f

typedef float f32x4 __attribute__((ext_vector_type(4)));
typedef __bf16 bf16x8 __attribute__((ext_vector_type(8)));
typedef __bf16 bf16x4 __attribute__((ext_vector_type(4)));

__device__ __forceinline__ f32x4 mfma16(bf16x8 a, bf16x8 b, f32x4 c) {
  return __builtin_amdgcn_mfma_f32_16x16x32_bf16(a, b, c, 0, 0, 0);
}

typedef __attribute__((address_space(1))) void gvoid;
typedef __attribute__((address_space(3))) void ldsvoid;

__device__ __forceinline__ void async16(void* lds, const void* g) {
  __builtin_amdgcn_global_load_lds((gvoid*)(uintptr_t)g, (ldsvoid*)(uintptr_t)lds, 16, 0, 0);
}

// raw barrier: no vmcnt drain (unlike __syncthreads); "memory" clobber pins
// LDS loads / stage intrinsics on their side of the barrier.
#define BAR() asm volatile("s_barrier" ::: "memory")
#define VMCNT(n) asm volatile("s_waitcnt vmcnt(" #n ")" ::: "memory")

// ---------------------------------------------------------------------------
// fp32 -> bf16 cast
// ---------------------------------------------------------------------------
__global__ __launch_bounds__(256) void cast_bf16(const float* __restrict__ src,
                                                 __bf16* __restrict__ dst, int n) {
  int i = (blockIdx.x * 256 + threadIdx.x) * 4;
  const int stride = gridDim.x * 1024;
  for (; i < n; i += stride) {
    const float4 v = *(const float4*)(src + i);
    bf16x4 o = {(__bf16)v.x, (__bf16)v.y, (__bf16)v.z, (__bf16)v.w};
    *(bf16x4*)(dst + i) = o;
  }
}

// ---------------------------------------------------------------------------
// QKV GEMM, 256x256 tile, BK=64, 8 waves (2Mx4N), 8-phase pipelined schedule.
// C[M][N] = A[M][K] * B[N][K]^T; K=2048 (32 K-tiles, 16 iterations).
// LDS 128KiB: 2 buffers x { A[2 halves][128][64], B[2 halves][128][64] } bf16.
// Bank-conflict swizzle (R3 fix): 3-bit chunk XOR within each 128B row —
// LDS[row][chunk] holds G[row][chunk ^ (row&7)]; applied as pre-swizzled
// GLOBAL source (linear global_load_lds dest) + same XOR on ds_read (rule 21).
// Reads: 64 lanes hit 16 rows x fixed chunk -> (row&7) XOR spreads each
// 8-lane exec group across all 8 16B slots -> conflict-free.
// Schedule (per iter i: p0-3 compute buf0=tile 2i, p4-7 buf1=tile 2i+1):
//   p0: issue buf1.A1,A3(t=2i+1); vmcnt(8); BAR; read Ball+Aq0; MFMA16; BAR
//   p1: read Aq1; issue buf0.B0,B1(t=2i+2);             BAR; MFMA16; BAR
//   p2: read Aq2; issue buf0.B2,B3,A0,A2(t=2i+2);       BAR; MFMA16; BAR
//   p3: read Aq3;                                       BAR; MFMA16; BAR
//   p4: issue buf0.A1,A3(t=2i+2); vmcnt(8); BAR; read Ball+Aq0; MFMA16; BAR
//   p5: read Aq1; issue buf1.B0,B1(t=2i+3);             BAR; MFMA16; BAR
//   p6: read Aq2; issue buf1.B2,B3,A0,A2(t=2i+3);       BAR; MFMA16; BAR
//   p7: read Aq3;                                       BAR; MFMA16; BAR
// ---------------------------------------------------------------------------
#define RA 0
#define RB 32768
#define BUF1 65536

#define READ_B(Bb) do { \
    bfr[0][0]=ldf(Bb,rB,0);      bfr[0][1]=ldf(Bb,rB,1); \
    bfr[1][0]=ldf(Bb,rB+16,0);   bfr[1][1]=ldf(Bb,rB+16,1); \
    bfr[2][0]=ldf(Bb,rB+32,0);   bfr[2][1]=ldf(Bb,rB+32,1); \
    bfr[3][0]=ldf(Bb,rB+48,0);   bfr[3][1]=ldf(Bb,rB+48,1); } while(0)

#define READ_A(Ab,P) do { \
    afr[0][0]=ldf(Ab,(P*2+0)*16+a,0); afr[0][1]=ldf(Ab,(P*2+0)*16+a,1); \
    afr[1][0]=ldf(Ab,(P*2+1)*16+a,0); afr[1][1]=ldf(Ab,(P*2+1)*16+a,1); } while(0)

#define DO_MFMA(P) do { __builtin_amdgcn_s_setprio(1); \
    _Pragma("unroll") for (int f_=0; f_<2; ++f_) \
    _Pragma("unroll") for (int n_=0; n_<4; ++n_) \
    _Pragma("unroll") for (int k_=0; k_<2; ++k_) \
      acc[P*2+f_][n_] = mfma16(afr[f_][k_], bfr[n_][k_], acc[P*2+f_][n_]); \
    __builtin_amdgcn_s_setprio(0); } while(0)

__global__ __launch_bounds__(512, 2) void qkv256(
    const __bf16* __restrict__ A, const __bf16* __restrict__ Bm,
    __bf16* __restrict__ Qb, __bf16* __restrict__ Kb, __bf16* __restrict__ Vtb,
    const float* __restrict__ bq, const float* __restrict__ bk,
    const float* __restrict__ bv) {
  extern __shared__ __align__(16) char Lds[];
  const int tid = threadIdx.x;
  const int l = tid & 63, w = tid >> 6;
  const int a = l & 15, g = l >> 4;
  const int wm = w >> 2, wn = w & 3;
  const int mbase = blockIdx.y * 256, nbase = blockIdx.x * 256;
  const int wbyte = w * 1024;
  const char* Ag = (const char*)A;
  const char* Bg = (const char*)Bm;
  const int rB = (wn & 1) * 64 + a;

  f32x4 acc[8][4] = {};
  bf16x8 bfr[4][2], afr[2][2];

  // stage one 8KB op: op j = half (j>>1), rows (j&1)*64..+63 of a [2][128][64]
  // bf16 region. LDS dest linear; global source chunk pre-swizzled by row&7.
  auto issue = [&](int bufofs, int regofs, const char* gmat, int grow0, int kt, int j) {
    const int grow = grow0 + (j >> 1) * 128 + (j & 1) * 64 + (tid >> 3);
    const int scol = (((tid & 7) ^ ((tid >> 3) & 7)) * 16);
    async16(Lds + bufofs + regofs + j * 8192 + wbyte,
            gmat + (size_t)grow * (DIMC * 2) + kt * 128 + scol);
  };
  // swizzled fragment read: 16B at (row, k-slice ks); chunk ^= row&7.
  auto ldf = [&](const char* halfbase, int row, int ks) -> bf16x8 {
    const int c = (ks * 64 + g * 16) ^ ((row & 7) << 4);
    return *(const bf16x8*)(halfbase + row * 128 + c);
  };

  // prologue: buf0 <- tile0 (all 8 ops), buf1 <- tile1 (first 6 ops)
  issue(0, RB, Bg, nbase, 0, 0); issue(0, RB, Bg, nbase, 0, 1);
  issue(0, RB, Bg, nbase, 0, 2); issue(0, RB, Bg, nbase, 0, 3);
  issue(0, RA, Ag, mbase, 0, 0); issue(0, RA, Ag, mbase, 0, 2);
  issue(0, RA, Ag, mbase, 0, 1); issue(0, RA, Ag, mbase, 0, 3);
  issue(BUF1, RB, Bg, nbase, 1, 0); issue(BUF1, RB, Bg, nbase, 1, 1);
  issue(BUF1, RB, Bg, nbase, 1, 2); issue(BUF1, RB, Bg, nbase, 1, 3);
  issue(BUF1, RA, Ag, mbase, 1, 0); issue(BUF1, RA, Ag, mbase, 1, 2);

  const char* A0 = Lds + wm * 16384;
  const char* B0 = Lds + RB + (wn >> 1) * 16384;
  const char* A1 = A0 + BUF1;
  const char* B1 = B0 + BUF1;

  for (int i = 0; i < 16; ++i) {
    const bool more = (i < 15);
    const int t2 = 2 * i + 2, t3 = 2 * i + 3;
    // ---- p0 ----
    issue(BUF1, RA, Ag, mbase, 2 * i + 1, 1);
    issue(BUF1, RA, Ag, mbase, 2 * i + 1, 3);
    VMCNT(8); BAR();
    READ_B(B0); READ_A(A0, 0);
    DO_MFMA(0); BAR();
    // ---- p1 ----
    READ_A(A0, 1);
    if (more) { issue(0, RB, Bg, nbase, t2, 0); issue(0, RB, Bg, nbase, t2, 1); }
    BAR(); DO_MFMA(1); BAR();
    // ---- p2 ----
    READ_A(A0, 2);
    if (more) { issue(0, RB, Bg, nbase, t2, 2); issue(0, RB, Bg, nbase, t2, 3);
                issue(0, RA, Ag, mbase, t2, 0); issue(0, RA, Ag, mbase, t2, 2); }
    BAR(); DO_MFMA(2); BAR();
    // ---- p3 ----
    READ_A(A0, 3);
    BAR(); DO_MFMA(3); BAR();
    // ---- p4 ----
    if (more) { issue(0, RA, Ag, mbase, t2, 1); issue(0, RA, Ag, mbase, t2, 3);
                VMCNT(8); } else { VMCNT(0); }
    BAR();
    READ_B(B1); READ_A(A1, 0);
    DO_MFMA(0); BAR();
    // ---- p5 ----
    READ_A(A1, 1);
    if (more) { issue(BUF1, RB, Bg, nbase, t3, 0); issue(BUF1, RB, Bg, nbase, t3, 1); }
    BAR(); DO_MFMA(1); BAR();
    // ---- p6 ----
    READ_A(A1, 2);
    if (more) { issue(BUF1, RB, Bg, nbase, t3, 2); issue(BUF1, RB, Bg, nbase, t3, 3);
                issue(BUF1, RA, Ag, mbase, t3, 0); issue(BUF1, RA, Ag, mbase, t3, 2); }
    BAR(); DO_MFMA(2); BAR();
    // ---- p7 ----
    READ_A(A1, 3);
    BAR(); DO_MFMA(3); BAR();
  }

  // epilogue: bias + scatter Q[B,H,N,D]*scale, K[B,H,N,D], Vt[B,H,D,N]
  const int seg = nbase >> 11;
  const int cin = (nbase & 2047) + wn * 64;
  const float* bias = (seg == 0) ? bq : ((seg == 1) ? bk : bv);
  const float scl = (seg == 0) ? QSCALE : 1.0f;
#pragma unroll
  for (int n = 0; n < 4; ++n) {
    const int c = cin + n * 16 + a;
    const float bb = bias[c];
    const int h = c >> 7, d = c & 127;
#pragma unroll
    for (int m = 0; m < 8; ++m) {
      const int mr = mbase + wm * 128 + m * 16 + g * 4;
      const int b_ = mr >> 11, sq = mr & 2047;
      f32x4 v = acc[m][n];
      if (seg == 2) {
        __bf16* dst = Vtb + ((size_t)(b_ * NH + h) * HD + d) * NSEQ + sq;
        bf16x4 pk = {(__bf16)(v[0] + bb), (__bf16)(v[1] + bb),
                     (__bf16)(v[2] + bb), (__bf16)(v[3] + bb)};
        *(bf16x4*)dst = pk;
      } else {
        __bf16* dst = ((seg == 0) ? Qb : Kb) +
                      ((size_t)(b_ * NH + h) * NSEQ + sq) * HD + d;
#pragma unroll
        for (int j = 0; j < 4; ++j) dst[(size_t)j * HD] = (__bf16)((v[j] + bb) * scl);
      }
    }
  }
}

// ---------------------------------------------------------------------------
// m97-structure 128x128 GEMM for the output projection.
// ---------------------------------------------------------------------------
__global__ __launch_bounds__(256) void gemm_out(
    const __bf16* __restrict__ A, const __bf16* __restrict__ Bm,
    const float* __restrict__ bias0, float* __restrict__ outp) {
  __shared__ __bf16 Al[128 * 32];
  __shared__ __bf16 Bl[128 * 32];
  const int tid = threadIdx.x;
  const int w = tid >> 6, l = tid & 63;
  const int a = l & 15, g = l >> 4;
  const int mbase = blockIdx.y * 128, nbase = blockIdx.x * 128;
  const int wr = w >> 1, wc = w & 1;

  f32x4 acc[4][4] = {};

  const char* Ag = (const char*)A +
      ((size_t)(mbase + w * 32 + (l >> 2)) * DIMC + (size_t)(l & 3) * 8) * 2;
  const char* Bg = (const char*)Bm +
      ((size_t)(nbase + w * 32 + (l >> 2)) * DIMC + (size_t)(l & 3) * 8) * 2;
  char* Alw = (char*)Al + w * 2048;
  char* Blw = (char*)Bl + w * 2048;

  for (int kt = 0; kt < DIMC / 32; ++kt) {
    const size_t ko = (size_t)kt * 64;
    async16(Alw, Ag + ko);
    async16(Alw + 1024, Ag + (size_t)16 * (DIMC * 2) + ko);
    async16(Blw, Bg + ko);
    async16(Blw + 1024, Bg + (size_t)16 * (DIMC * 2) + ko);
    __syncthreads();
    bf16x8 af[4], bf_[4];
#pragma unroll
    for (int m = 0; m < 4; ++m)
      af[m] = *(const bf16x8*)((const char*)Al + (wr * 64 + m * 16 + a) * 64 + g * 16);
#pragma unroll
    for (int n = 0; n < 4; ++n)
      bf_[n] = *(const bf16x8*)((const char*)Bl + (wc * 64 + n * 16 + a) * 64 + g * 16);
#pragma unroll
    for (int m = 0; m < 4; ++m)
#pragma unroll
      for (int n = 0; n < 4; ++n) acc[m][n] = mfma16(af[m], bf_[n], acc[m][n]);
    __syncthreads();
  }

#pragma unroll
  for (int n = 0; n < 4; ++n) {
    const int c = nbase + wc * 64 + n * 16 + a;
    const float bb = bias0[c];
#pragma unroll
    for (int m = 0; m < 4; ++m) {
      const int mr = mbase + wr * 64 + m * 16 + g * 4;
      float* dst = outp + (size_t)mr * DIMC + c;
      f32x4 v = acc[m][n];
#pragma unroll
      for (int j = 0; j < 4; ++j) dst[(size_t)j * DIMC] = v[j] + bb;
    }
  }
}

// ---------------------------------------------------------------------------
// Sliding-window flash attention (unchanged from validated baseline).
// ---------------------------------------------------------------------------
__global__ __launch_bounds__(256) void attn_swa(const __bf16* __restrict__ Qb,
                                                const __bf16* __restrict__ Kb,
                                                const __bf16* __restrict__ Vtb,
                                                __bf16* __restrict__ Ob) {
  __shared__ __bf16 Klds[64 * 128];
  __shared__ __bf16 Vlds[128 * 64];
  __shared__ __bf16 Plds[4 * 16 * 64];
  const int tid = threadIdx.x;
  const int w = tid >> 6, l = tid & 63;
  const int a = l & 15, g = l >> 4;
  const int bh = blockIdx.y;
  const int qbase = blockIdx.x * 64;
  const __bf16* Qg = Qb + (size_t)bh * NSEQ * HD + (size_t)qbase * HD;
  const __bf16* Kg = Kb + (size_t)bh * NSEQ * HD;
  const __bf16* Vg = Vtb + (size_t)bh * HD * NSEQ;

  bf16x8 qf[4];
#pragma unroll
  for (int s = 0; s < 4; ++s)
    qf[s] = *(const bf16x8*)(Qg + (size_t)(w * 16 + a) * HD + s * 32 + g * 8);

  float mrow[4] = {-1e38f, -1e38f, -1e38f, -1e38f};
  float lrow[4] = {0.f, 0.f, 0.f, 0.f};
  f32x4 o[8] = {};

  const int ktlo = (qbase >= 1024) ? ((qbase - 1024) >> 6) : 0;
  const int kthi = qbase >> 6;
  const int qmax = qbase + 63;

  for (int kt = ktlo; kt <= kthi; ++kt) {
    const int kb = kt * 64;
#pragma unroll
    for (int j = 0; j < 4; ++j) {
      const int off = j * 4096 + w * 1024 + l * 16;
      const int row = off >> 8;
      const int cg = ((off >> 4) & 15) ^ (row & 7);
      async16((char*)Klds + j * 4096 + w * 1024,
              (const char*)Kg + (size_t)(kb + row) * 256 + cg * 16);
    }
#pragma unroll
    for (int j = 0; j < 4; ++j) {
      const int off = j * 4096 + w * 1024 + l * 16;
      const int row = off >> 7;
      const int cg = ((off >> 4) & 7) ^ (row & 7);
      async16((char*)Vlds + j * 4096 + w * 1024,
              (const char*)Vg + (size_t)row * (NSEQ * 2) + (size_t)kb * 2 + cg * 16);
    }
    __syncthreads();

    const bool full = (kb >= qmax - 1024) && (kb + 63 <= qbase);
    f32x4 s4[4];
#pragma unroll
    for (int t = 0; t < 4; ++t) {
      f32x4 sc = {};
#pragma unroll
      for (int ds = 0; ds < 4; ++ds) {
        const int row = t * 16 + a;
        const int ch = (ds * 4 + g) ^ (row & 7);
        bf16x8 kf = *(const bf16x8*)((const char*)Klds + row * 256 + ch * 16);
        sc = mfma16(qf[ds], kf, sc);
      }
      s4[t] = sc;
    }
    if (!full) {
#pragma unroll
      for (int t = 0; t < 4; ++t)
#pragma unroll
        for (int i = 0; i < 4; ++i) {
          const int q = qbase + w * 16 + g * 4 + i;
          const int kv = kb + t * 16 + a;
          if (kv > q || kv + 1024 < q) s4[t][i] = -1e30f;
        }
    }
    float pm[4], corr[4], rs[4];
#pragma unroll
    for (int i = 0; i < 4; ++i)
      pm[i] = fmaxf(fmaxf(s4[0][i], s4[1][i]), fmaxf(s4[2][i], s4[3][i]));
#pragma unroll
    for (int i = 0; i < 4; ++i) {
      pm[i] = fmaxf(pm[i], __shfl_xor(pm[i], 1));
      pm[i] = fmaxf(pm[i], __shfl_xor(pm[i], 2));
      pm[i] = fmaxf(pm[i], __shfl_xor(pm[i], 4));
      pm[i] = fmaxf(pm[i], __shfl_xor(pm[i], 8));
      const float nm = fmaxf(mrow[i], pm[i]);
      corr[i] = __expf(mrow[i] - nm);
      mrow[i] = nm;
      rs[i] = 0.f;
    }
#pragma unroll
    for (int t = 0; t < 4; ++t)
#pragma unroll
      for (int i = 0; i < 4; ++i) {
        const float p = __expf(s4[t][i] - mrow[i]);
        s4[t][i] = p;
        rs[i] += p;
      }
#pragma unroll
    for (int i = 0; i < 4; ++i) {
      rs[i] += __shfl_xor(rs[i], 1);
      rs[i] += __shfl_xor(rs[i], 2);
      rs[i] += __shfl_xor(rs[i], 4);
      rs[i] += __shfl_xor(rs[i], 8);
      lrow[i] = lrow[i] * corr[i] + rs[i];
    }
#pragma unroll
    for (int n = 0; n < 8; ++n)
#pragma unroll
      for (int i = 0; i < 4; ++i) o[n][i] *= corr[i];
    char* Pw = (char*)Plds + w * 2048;
#pragma unroll
    for (int t = 0; t < 4; ++t)
#pragma unroll
      for (int i = 0; i < 4; ++i) {
        const int q = g * 4 + i;
        const int byte = (q * 128 + (t * 16 + a) * 2) ^ ((q & 7) << 4);
        *(__bf16*)(Pw + byte) = (__bf16)s4[t][i];
      }
#pragma unroll
    for (int ks = 0; ks < 2; ++ks) {
      const int ch = (ks * 4 + g) ^ (a & 7);
      bf16x8 pa = *(const bf16x8*)(Pw + a * 128 + ch * 16);
#pragma unroll
      for (int n = 0; n < 8; ++n) {
        const int row = n * 16 + a;
        const int vch = (ks * 4 + g) ^ (row & 7);
        bf16x8 vf = *(const bf16x8*)((const char*)Vlds + row * 128 + vch * 16);
        o[n] = mfma16(pa, vf, o[n]);
      }
    }
    __syncthreads();
  }

  const int b_ = bh >> 4, h = bh & 15;
  __bf16* Og = Ob + (size_t)(b_ * NSEQ + qbase + w * 16 + g * 4) * DIMC + h * HD;
#pragma unroll
  for (int i = 0; i < 4; ++i) {
    const float inv = 1.f / lrow[i];
#pragma unroll
    for (int n = 0; n < 8; ++n)
      Og[(size_t)i * DIMC + n * 16 + a] = (__bf16)(o[n][i] * inv);
  }
}

// ---------------------------------------------------------------------------
extern "C" void kernel_launch(void* const* d_in, const int* in_sizes, int n_in,
                              void* d_out, int out_size, void* d_ws, size_t ws_size,
                              hipStream_t stream) {
  const float* x = (const float*)d_in[0];
  const float* Wq = (const float*)d_in[1];
  const float* bq = (const float*)d_in[2];
  const float* Wk = (const float*)d_in[3];
  const float* bk = (const float*)d_in[4];
  const float* Wv = (const float*)d_in[5];
  const float* bv = (const float*)d_in[6];
  const float* Wo = (const float*)d_in[7];
  const float* bo = (const float*)d_in[8];
  float* out = (float*)d_out;

  char* ws = (char*)d_ws;
  __bf16* xb    = (__bf16*)(ws + 0);          // 16.78 MB (reused as Ob)
  __bf16* Wqkvb = (__bf16*)(ws + 16777216);   // 25.17 MB
  __bf16* Wob   = (__bf16*)(ws + 41943040);   // 8.39 MB
  __bf16* Qb    = (__bf16*)(ws + 50331648);   // 16.78 MB
  __bf16* Kb    = (__bf16*)(ws + 67108864);   // 16.78 MB
  __bf16* Vtb   = (__bf16*)(ws + 83886080);   // 16.78 MB -> total 100.66 MB
  __bf16* Ob    = xb;

  (void)hipFuncSetAttribute((const void*)qkv256,
                            hipFuncAttributeMaxDynamicSharedMemorySize, 131072);

  cast_bf16<<<dim3(2048), 256, 0, stream>>>(x, xb, MROWS * DIMC);
  cast_bf16<<<dim3(1024), 256, 0, stream>>>(Wq, Wqkvb, DIMC * DIMC);
  cast_bf16<<<dim3(1024), 256, 0, stream>>>(Wk, Wqkvb + (size_t)DIMC * DIMC, DIMC * DIMC);
  cast_bf16<<<dim3(1024), 256, 0, stream>>>(Wv, Wqkvb + (size_t)2 * DIMC * DIMC, DIMC * DIMC);
  cast_bf16<<<dim3(1024), 256, 0, stream>>>(Wo, Wob, DIMC * DIMC);

  qkv256<<<dim3(NQKV / 256, MROWS / 256), 512, 131072, stream>>>(
      xb, Wqkvb, Qb, Kb, Vtb, bq, bk, bv);

  attn_swa<<<dim3(NSEQ / 64, BATCH * NH), 256, 0, stream>>>(Qb, Kb, Vtb, Ob);

  gemm_out<<<dim3(DIMC / 128, MROWS / 128), 256, 0, stream>>>(
      Ob, Wob, bo, out);
}